// Round 3
// baseline (263.495 us; speedup 1.0000x reference)
//
#include <hip/hip_runtime.h>
#include <math.h>

#define LOG2PI_F 1.8378770664093453f

typedef float vf4 __attribute__((ext_vector_type(4)));  // clang-native vec for nontemporal store

// Part B first (blockIdx < partB_blocks): one thread per pair -> integral.
// Part A: one thread per FOUR (pair,q) points -> two vf4 nontemporal
// stores (16 B/lane). 4x fewer waves/blocks than 1-point-per-thread; the
// R0 version was wave/dispatch-overhead bound (~120us vs 37us roofline).
__global__ __launch_bounds__(256) void gauss2d_kernel(
    const float* __restrict__ tv_means,     // [B,2]
    const float* __restrict__ tv_covars,    // [B,2,2]
    const float* __restrict__ rotations,    // [B,2,2]
    const float* __restrict__ translations, // [B,2]
    const float* __restrict__ eta,          // [2,49]
    const float* __restrict__ weights,      // [49]
    float* __restrict__ gauss_pts,          // [B,49,2]
    float* __restrict__ integral,           // [B]
    unsigned int B,
    unsigned int partB_blocks)
{
    if (blockIdx.x < partB_blocks) {
        // ---- integral: one thread per pair ----
        unsigned int p = blockIdx.x * 256u + threadIdx.x;
        if (p >= B) return;

        const float4 R  = ((const float4*)rotations)[p];     // R00,R01,R10,R11
        const float2 tr = ((const float2*)translations)[p];
        const float2 mu = ((const float2*)tv_means)[p];
        const float4 C  = ((const float4*)tv_covars)[p];     // c00,c01,c10,c11

        float det     = C.x * C.w - C.y * C.z;
        float inv_det = 1.0f / det;
        float lognorm = fmaf(-0.5f, __logf(det), -LOG2PI_F);
        float c01p10  = C.y + C.z;

        float s = 0.0f;
        #pragma unroll 7
        for (int q = 0; q < 49; ++q) {
            float ex = eta[q];
            float ey = eta[49 + q];
            float gx = fmaf(R.x, ex, fmaf(R.y, ey, tr.x));
            float gy = fmaf(R.z, ex, fmaf(R.w, ey, tr.y));
            float dx = gx - mu.x;
            float dy = gy - mu.y;
            float quad = (C.w * dx * dx - c01p10 * dx * dy + C.x * dy * dy) * inv_det;
            s += weights[q] * __expf(fmaf(-0.5f, quad, lognorm));
        }
        integral[p] = fminf(fmaxf(s, 0.0f), 1.0f);
    } else {
        // ---- gauss_pts: one thread per 4 consecutive (pair,q) points ----
        const unsigned int NP = B * 49u;                      // total points
        unsigned int tid = (blockIdx.x - partB_blocks) * 256u + threadIdx.x;
        unsigned int t0  = tid * 4u;
        if (t0 >= NP) return;

        unsigned int p0 = t0 / 49u;                           // magic-mul div
        unsigned int q0 = t0 - p0 * 49u;

        float4 R0 = ((const float4*)rotations)[p0];
        float2 T0 = ((const float2*)translations)[p0];
        float4 R1 = R0;
        float2 T1 = T0;
        if (q0 >= 46u && p0 + 1u < B) {                       // 4-point span crosses pair
            R1 = ((const float4*)rotations)[p0 + 1u];
            T1 = ((const float2*)translations)[p0 + 1u];
        }

        if (t0 + 4u <= NP) {                                  // full quad (always for ref shapes)
            float o[8];
            #pragma unroll
            for (int j = 0; j < 4; ++j) {
                unsigned int q = q0 + (unsigned)j;
                bool cross = q >= 49u;
                q = cross ? q - 49u : q;
                float4 R = cross ? R1 : R0;
                float2 T = cross ? T1 : T0;
                float ex = eta[q];
                float ey = eta[49u + q];
                o[2*j]   = fmaf(R.x, ex, fmaf(R.y, ey, T.x));
                o[2*j+1] = fmaf(R.z, ex, fmaf(R.w, ey, T.y));
            }
            vf4* dst = (vf4*)(gauss_pts + (size_t)t0 * 2u);
            vf4 v0 = { o[0], o[1], o[2], o[3] };
            vf4 v1 = { o[4], o[5], o[6], o[7] };
            __builtin_nontemporal_store(v0, dst);
            __builtin_nontemporal_store(v1, dst + 1);
        } else {                                              // generic tail
            for (unsigned int t = t0; t < NP; ++t) {
                unsigned int q = t - t0 + q0;
                bool cross = q >= 49u;
                q = cross ? q - 49u : q;
                float4 R = cross ? R1 : R0;
                float2 T = cross ? T1 : T0;
                float ex = eta[q];
                float ey = eta[49u + q];
                gauss_pts[(size_t)t*2u]      = fmaf(R.x, ex, fmaf(R.y, ey, T.x));
                gauss_pts[(size_t)t*2u + 1u] = fmaf(R.z, ex, fmaf(R.w, ey, T.y));
            }
        }
    }
}

extern "C" void kernel_launch(void* const* d_in, const int* in_sizes, int n_in,
                              void* d_out, int out_size, void* d_ws, size_t ws_size,
                              hipStream_t stream) {
    const float* tv_means     = (const float*)d_in[0];
    const float* tv_covars    = (const float*)d_in[1];
    const float* rotations    = (const float*)d_in[2];
    const float* translations = (const float*)d_in[3];
    const float* eta          = (const float*)d_in[4];
    const float* weights      = (const float*)d_in[5];

    const unsigned int B = (unsigned int)(in_sizes[0] / 2);   // [B,2] means
    float* gauss_pts = (float*)d_out;                          // first B*98 floats
    float* integral  = (float*)d_out + (size_t)B * 98u;        // then B floats

    const unsigned int partB_blocks = (B + 255u) / 256u;
    const size_t NP = (size_t)B * 49u;
    const unsigned int partA_threads_div4 = (unsigned int)((NP + 3u) / 4u);
    const unsigned int partA_blocks = (partA_threads_div4 + 255u) / 256u;

    dim3 grid(partA_blocks + partB_blocks);
    dim3 block(256);
    hipLaunchKernelGGL(gauss2d_kernel, grid, block, 0, stream,
                       tv_means, tv_covars, rotations, translations,
                       eta, weights, gauss_pts, integral, B, partB_blocks);
}